// Round 10
// baseline (156.705 us; speedup 1.0000x reference)
//
#include <hip/hip_runtime.h>
#include <stdint.h>

// RelativeAttention (Transformer-XL style), MI355X bf16-MFMA pipeline.
// SEQ=1024 RLEN=2048 BATCH=4 NH=16 DH=64 DM=1024.
// rel_shift derivation: shifted_bd[i,j] = BD[i, 1024 + j - i].

typedef __attribute__((ext_vector_type(8))) short v8s;    // 8 x bf16
typedef __attribute__((ext_vector_type(4))) float v4f;    // MFMA acc
typedef __attribute__((ext_vector_type(4))) uint32_t v4u;

__device__ __forceinline__ uint16_t f2b(float x) {       // f32 -> bf16 RNE
    uint32_t u = __builtin_bit_cast(uint32_t, x);
    u += 0x7fffu + ((u >> 16) & 1u);
    return (uint16_t)(u >> 16);
}

__device__ __forceinline__ uint32_t cvtpk(float lo, float hi) {
    uint32_t r;
    asm("v_cvt_pk_bf16_f32 %0, %1, %2" : "=v"(r) : "v"(lo), "v"(hi));
    return r;
}

__device__ __forceinline__ void gld16(const void* g, void* lds) {
    __builtin_amdgcn_global_load_lds(
        (const __attribute__((address_space(1))) uint32_t*)g,
        (__attribute__((address_space(3))) uint32_t*)lds, 16, 0, 0);
}

// ---------------- prep: f32->bf16 casts (h, r, o_w) + weight transposes -----
__global__ __launch_bounds__(256) void prep_kernel(
    const float* __restrict__ h, const float* __restrict__ r,
    const float* __restrict__ o_w, const float* __restrict__ q_w,
    const float* __restrict__ k_w, const float* __restrict__ v_w,
    const float* __restrict__ r_w,
    uint64_t* __restrict__ hB, uint64_t* __restrict__ rB,
    uint64_t* __restrict__ owB, uint16_t* __restrict__ Wcat,
    uint16_t* __restrict__ rwT)
{
    __shared__ float t[64][65];
    const int bid = blockIdx.x, tid = threadIdx.x;
    if (bid < 1024) {
        const int tx = bid & 15, ty = (bid >> 4) & 15, z = bid >> 8;
        const int n0 = tx * 64, h0 = ty * 64;
        const float* src = (z == 0) ? q_w : (z == 1) ? k_w : (z == 2) ? v_w : r_w;
        uint16_t* dst = (z == 3) ? rwT : Wcat + (size_t)z * 1048576;
#pragma unroll
        for (int q = 0; q < 16; ++q) {
            int idx = q * 256 + tid, rr = idx >> 6, cc = idx & 63;
            t[rr][cc] = src[(size_t)(h0 + rr) * 1024 + n0 + cc];
        }
        __syncthreads();
#pragma unroll
        for (int q = 0; q < 16; ++q) {
            int idx = q * 256 + tid, rr = idx >> 6, cc = idx & 63;
            dst[(size_t)(n0 + rr) * 1024 + h0 + cc] = f2b(t[cc][rr]);
        }
    } else {
        const float4* h4 = (const float4*)h;
        const float4* r4 = (const float4*)r;
        const float4* w4 = (const float4*)o_w;
        const int total = 1048576 + 2097152 + 262144; // float4 chunks
        for (int i = (bid - 1024) * 256 + tid; i < total; i += 2048 * 256) {
            float4 v; uint64_t* dst; int idx;
            if (i < 1048576)      { idx = i;           v = h4[idx]; dst = hB; }
            else if (i < 3145728) { idx = i - 1048576; v = r4[idx]; dst = rB; }
            else                  { idx = i - 3145728; v = w4[idx]; dst = owB; }
            uint64_t p = (uint64_t)f2b(v.x) | ((uint64_t)f2b(v.y) << 16)
                       | ((uint64_t)f2b(v.z) << 32) | ((uint64_t)f2b(v.w) << 48);
            dst[idx] = p;
        }
    }
}

// ---------------- bf16 GEMM body, C = A[M,K] * B[N,K]^T, BMx128, BK=64 ------
// m97 structure: SINGLE-buffered LDS (32KB -> high occupancy; cross-block TLP
// covers the barrier drain — dbuf regressed (r6/m132), reg-staged A regressed
// (r9/m151): keep global_load_lds + single buffer).
template<int MODE, int MI>
__device__ __forceinline__ void gemm_body(
    const uint16_t* __restrict__ A, const uint16_t* __restrict__ B, int K,
    int bx, int by, uint16_t* As, uint16_t* Bs,
    uint16_t* __restrict__ o0, uint16_t* __restrict__ o1,
    uint16_t* __restrict__ o2, uint16_t* __restrict__ o3,
    float* __restrict__ fo, const float* __restrict__ fres)
{
    const int tid = threadIdx.x;
    const int w = tid >> 6, lane = tid & 63;
    const int g = lane >> 4, c15 = lane & 15;
    const int m0 = by * (MI * 32), n0 = bx * 128;
    const int wr = w >> 1, wc = w & 1;

    int rowA[MI], colA[MI];
#pragma unroll
    for (int q = 0; q < MI; ++q) {
        int D = (w * MI + q) * 1024 + lane * 16;
        int row = D >> 7;
        rowA[q] = row;
        colA[q] = (D & 127) ^ ((row & 7) << 4);
    }
    int rowB[4], colB[4];
#pragma unroll
    for (int q = 0; q < 4; ++q) {
        int D = (w * 4 + q) * 1024 + lane * 16;
        int row = D >> 7;
        rowB[q] = row;
        colB[q] = (D & 127) ^ ((row & 7) << 4);
    }

    v4f acc[MI][4];
#pragma unroll
    for (int i = 0; i < MI; ++i)
#pragma unroll
        for (int j = 0; j < 4; ++j) acc[i][j] = v4f{0.f, 0.f, 0.f, 0.f};

    const char* Abase = (const char*)(A + (size_t)m0 * K);
    const char* Bbase = (const char*)(B + (size_t)n0 * K);
    const size_t ld = (size_t)K * 2;

    for (int kb = 0; kb < K; kb += 64) {
        if (kb) __syncthreads();
#pragma unroll
        for (int q = 0; q < MI; ++q)
            gld16(Abase + (size_t)rowA[q] * ld + (size_t)kb * 2 + colA[q],
                  (char*)As + (w * MI + q) * 1024);
#pragma unroll
        for (int q = 0; q < 4; ++q)
            gld16(Bbase + (size_t)rowB[q] * ld + (size_t)kb * 2 + colB[q],
                  (char*)Bs + (w * 4 + q) * 1024);
        asm volatile("s_waitcnt vmcnt(0)" ::: "memory");
        __syncthreads();

        v8s af[MI][2], bf[4][2];
#pragma unroll
        for (int mi = 0; mi < MI; ++mi) {
            int row = wr * (MI * 16) + mi * 16 + c15;
#pragma unroll
            for (int ks = 0; ks < 2; ++ks) {
                int cl = ks * 64 + g * 16;
                af[mi][ks] = *(const v8s*)((const char*)As + row * 128 + (cl ^ ((row & 7) << 4)));
            }
        }
#pragma unroll
        for (int ni = 0; ni < 4; ++ni) {
            int row = wc * 64 + ni * 16 + c15;
#pragma unroll
            for (int ks = 0; ks < 2; ++ks) {
                int cl = ks * 64 + g * 16;
                bf[ni][ks] = *(const v8s*)((const char*)Bs + row * 128 + (cl ^ ((row & 7) << 4)));
            }
        }
#pragma unroll
        for (int mi = 0; mi < MI; ++mi)
#pragma unroll
            for (int ni = 0; ni < 4; ++ni)
#pragma unroll
                for (int ks = 0; ks < 2; ++ks)
                    acc[mi][ni] = __builtin_amdgcn_mfma_f32_16x16x32_bf16(
                        af[mi][ks], bf[ni][ks], acc[mi][ni], 0, 0, 0);
    }

#pragma unroll
    for (int mi = 0; mi < MI; ++mi)
#pragma unroll
        for (int ni = 0; ni < 4; ++ni)
#pragma unroll
            for (int t = 0; t < 4; ++t) {
                int row = m0 + wr * (MI * 16) + mi * 16 + g * 4 + t; // C row
                int col = n0 + wc * 64 + ni * 16 + c15;              // C col
                float v = acc[mi][ni][t];
                if (MODE == 0) {
                    int seg = col >> 10, nd = col & 1023;
                    int i = row >> 2, b = row & 3, n = nd >> 6, d = nd & 63;
                    int bn = b * 16 + n;
                    if (seg == 0) {
                        o0[(bn << 16) + (i << 6) + d] = f2b(v);  // raw Q (biases added in attn)
                    } else if (seg == 1) {
                        o2[(bn << 16) + (i << 6) + d] = f2b(v);
                    } else {
                        // V transposed + j-permuted within each 64-block:
                        // j = f*16+c stored at position c*4+f (must match P store)
                        int il = i & 63;
                        int iperm = (i & ~63) | ((il & 15) * 4 + (il >> 4));
                        o3[(bn << 16) + (d << 10) + iperm] = f2b(v);
                    }
                } else if (MODE == 1) {
                    int j = row >> 2, b = row & 3, n = col >> 6, d = col & 63;
                    int bn = b * 16 + n;
                    o0[(bn << 17) + (j << 6) + d] = f2b(v);
                } else {
                    size_t idx = (size_t)row * 1024 + col;
                    fo[idx] = v + fres[idx];   // residual add in f32
                }
            }
}

// merged projection GEMMs, 2D-XCD-swizzled (bid%8 = XCD)
__global__ __launch_bounds__(256) void gemm_qkvr(
    const uint16_t* __restrict__ hB, const uint16_t* __restrict__ Wcat,
    const uint16_t* __restrict__ rB, const uint16_t* __restrict__ rwT,
    uint16_t* __restrict__ Qraw, uint16_t* __restrict__ Kt,
    uint16_t* __restrict__ Vt, uint16_t* __restrict__ Kr)
{
    __shared__ __align__(16) uint16_t As[128 * 64];
    __shared__ __align__(16) uint16_t Bs[128 * 64];
    const int bid = blockIdx.x;
    if (bid < 768) {
        const int x = bid & 7, l = bid >> 3;          // l in [0,96)
        const int by = (x >> 1) * 8 + l / 12;
        const int bx = (x & 1) * 12 + l % 12;
        gemm_body<0, 4>(hB, Wcat, 1024, bx, by, As, Bs,
                        Qraw, nullptr, Kt, Vt, nullptr, nullptr);
    } else {
        const int b2 = bid - 768;
        const int x = b2 & 7, l = b2 >> 3;            // l in [0,64)
        const int by = x * 8 + l / 8;
        const int bx = l % 8;
        gemm_body<1, 4>(rB, rwT, 1024, bx, by, As, Bs,
                        Kr, nullptr, nullptr, nullptr, nullptr, nullptr);
    }
}

// out proj: BM=64 tiles -> 512 blocks, XCD x owns m-rows [8x,+8)
__global__ __launch_bounds__(256) void gemm_out(
    const uint16_t* __restrict__ AV, const uint16_t* __restrict__ owB,
    float* __restrict__ AO, const float* __restrict__ hres)
{
    __shared__ __align__(16) uint16_t As[64 * 64];
    __shared__ __align__(16) uint16_t Bs[128 * 64];
    const int x = blockIdx.x & 7, l = blockIdx.x >> 3;  // l in [0,64)
    const int by = x * 8 + l / 8;
    const int bx = l % 8;
    gemm_body<2, 2>(AV, owB, 1024, bx, by, As, Bs,
                    nullptr, nullptr, nullptr, nullptr, AO, hres);
}

// ---------------- fused rel-shift flash attention ---------------------------
// Grid 512 blocks x 512 threads (8 waves); XCD-swizzled (8 i-tiles of a bn
// share one XCD L2); 2 blocks/CU (80KB LDS), 16 waves/CU. Each wave owns ONE
// 16-row strip. Per j-tile: double-buffered K/V staging + 256-row Kr ring
// (64 new rows/tile, one chunk per wave) via global_load_lds with
// pre-swizzled source; rel-shift via 20 lane shuffles; FIXED-max softmax
// (M=8, exact by shift invariance). Q is stored RAW by the GEMM; r_w_bias /
// r_r_bias are added here (bf16 unpack + f32 add + cvt_pk repack, once per
// wave) producing qwf/qrf. P stored j-permuted (col' = c15*4+jf); V permuted
// identically in gemm<0>.
__global__ __launch_bounds__(512, 4) void attn_kernel(
    const uint16_t* __restrict__ Qraw, const uint16_t* __restrict__ Kt,
    const uint16_t* __restrict__ Vt, const uint16_t* __restrict__ Kr,
    const float* __restrict__ bw, const float* __restrict__ br,
    uint16_t* __restrict__ AV)
{
    __shared__ __align__(16) uint16_t Ks[2][4096];   // 8KB ea: 64 j x 64 d
    __shared__ __align__(16) uint16_t Vs[2][4096];   // 8KB ea: 64 d x 64 j'
    __shared__ __align__(16) uint16_t Krs[16384];    // 32KB ring: 256 rows
    __shared__ __align__(16) uint16_t Ptl[8][1024];  // 16KB: per-wave 16x64

    const int tid = threadIdx.x, w = tid >> 6, lane = tid & 63;
    const int g = lane >> 4, c15 = lane & 15;
    const int bid = blockIdx.x;
    const int xcd = bid & 7, slot = bid >> 3;
    const int it = slot & 7, bn = ((slot >> 3) << 3) | xcd;
    const int b = bn >> 4, n = bn & 15;
    const int i0 = it * 128, i0w = i0 + w * 16;
    const int B0 = 897 - i0;                 // lowest Kr row of jt=0 window

    const uint16_t* qp = Qraw + ((size_t)bn << 16);
    const char* ktp = (const char*)(Kt + ((size_t)bn << 16));
    const char* vtp = (const char*)(Vt + ((size_t)bn << 16));
    const char* krp = (const char*)(Kr + ((size_t)bn << 17));

    const int rsub = lane >> 3;              // staging: row-within-8-chunk
    const int csrc = ((lane & 7) ^ rsub) << 4;  // pre-swizzled source col
    const int dsto = lane * 16;              // linear LDS dest
    const int swz = (c15 & 7) << 4;          // read-side XOR term

    // rel-shift shuffle constants: e = 15 + c15 - (g*4+t)
    int sl[4], esel[4];
#pragma unroll
    for (int t = 0; t < 4; ++t) {
        int e = 15 + c15 - (g * 4 + t);
        sl[t] = g * 16 + (e & 15);
        esel[t] = e >> 4;
    }

    // Q load (raw) + bias add -> qwf (with r_w_bias), qrf (with r_r_bias)
    const float* bwn = bw + n * 64;
    const float* brn = br + n * 64;
    v8s qwf[2], qrf[2];
#pragma unroll
    for (int ks = 0; ks < 2; ++ks) {
        v8s raw = *(const v8s*)(qp + ((i0w + c15) << 6) + ks * 32 + g * 8);
        const int db = ks * 32 + g * 8;
        float4 w0 = *(const float4*)(bwn + db), w1 = *(const float4*)(bwn + db + 4);
        float4 r0 = *(const float4*)(brn + db), r1 = *(const float4*)(brn + db + 4);
        float f[8];
#pragma unroll
        for (int j = 0; j < 8; ++j)
            f[j] = __builtin_bit_cast(float, (uint32_t)(uint16_t)raw[j] << 16);
        v4u pw, pr;
        pw.x = cvtpk(f[0] + w0.x, f[1] + w0.y);
        pw.y = cvtpk(f[2] + w0.z, f[3] + w0.w);
        pw.z = cvtpk(f[4] + w1.x, f[5] + w1.y);
        pw.w = cvtpk(f[6] + w1.z, f[7] + w1.w);
        pr.x = cvtpk(f[0] + r0.x, f[1] + r0.y);
        pr.y = cvtpk(f[2] + r0.z, f[3] + r0.w);
        pr.z = cvtpk(f[4] + r1.x, f[5] + r1.y);
        pr.w = cvtpk(f[6] + r1.z, f[7] + r1.w);
        qwf[ks] = __builtin_bit_cast(v8s, pw);
        qrf[ks] = __builtin_bit_cast(v8s, pr);
    }

    v4f acc_o[4];
    float psac[4];
#pragma unroll
    for (int df = 0; df < 4; ++df) acc_o[df] = v4f{0.f, 0.f, 0.f, 0.f};
#pragma unroll
    for (int t = 0; t < 4; ++t) psac[t] = 0.f;

    uint16_t* Ptw = Ptl[w];
    const float SCL = 0.18033688f;   // 0.125 * log2(e)
    const float MB8 = 11.54156032f;  // 8 * log2(e)

    // ---- prologue staging: K/V tile 0 (chunk w each) + Kr rows B0..B0+191
    gld16(ktp + (size_t)(w * 8 + rsub) * 128 + csrc,
          (char*)Ks[0] + w * 1024 + dsto);
    gld16(vtp + (size_t)(w * 8 + rsub) * 2048 + csrc,
          (char*)Vs[0] + w * 1024 + dsto);
#pragma unroll
    for (int qq = 0; qq < 3; ++qq) {
        const int chunk = qq * 8 + w;
        const int rg = B0 + chunk * 8 + rsub;   // in [1, 1088]
        gld16(krp + (size_t)rg * 128 + csrc, (char*)Krs + chunk * 1024 + dsto);
    }
    asm volatile("s_waitcnt vmcnt(0)" ::: "memory");
    __syncthreads();

    for (int jt = 0; jt < 16; ++jt) {
        const int cur = jt & 1;
        if (jt < 15) {
            const int j1 = (jt + 1) * 64;
            gld16(ktp + (size_t)(j1 + w * 8 + rsub) * 128 + csrc,
                  (char*)Ks[cur ^ 1] + w * 1024 + dsto);
            gld16(vtp + (size_t)(w * 8 + rsub) * 2048 + j1 * 2 + csrc,
                  (char*)Vs[cur ^ 1] + w * 1024 + dsto);
            const int sbase = (192 + 64 * jt) & 255;   // ring write slots
            int rg = B0 + 192 + 64 * jt + w * 8 + rsub;
            rg = rg > 2047 ? 2047 : rg;  // clamp: only u=79 (never gathered)
            gld16(krp + (size_t)rg * 128 + csrc,
                  (char*)Krs + (sbase + w * 8) * 128 + dsto);
        }

        // --- AC = Qw x K^T (64 cols) + BD = Qr x KrWin^T (80 cols) ---
        v4f ac[4];
#pragma unroll
        for (int jf = 0; jf < 4; ++jf) ac[jf] = v4f{0.f, 0.f, 0.f, 0.f};
        v4f pp[5];
#pragma unroll
        for (int pf = 0; pf < 5; ++pf) pp[pf] = v4f{0.f, 0.f, 0.f, 0.f};

        __builtin_amdgcn_s_setprio(1);
#pragma unroll
        for (int jf = 0; jf < 4; ++jf) {
            const char* krow = (const char*)Ks[cur] + (jf * 16 + c15) * 128;
#pragma unroll
            for (int ks = 0; ks < 2; ++ks) {
                v8s kf = *(const v8s*)(krow + ((ks * 64 + g * 16) ^ swz));
                ac[jf] = __builtin_amdgcn_mfma_f32_16x16x32_bf16(qwf[ks], kf, ac[jf], 0, 0, 0);
            }
        }
        const int krbase = 64 * jt + 112 - 16 * w + c15;  // ring slot (+c15)
#pragma unroll
        for (int pf = 0; pf < 5; ++pf) {
            const int sltr = (krbase + 16 * pf) & 255;
            const char* krow = (const char*)Krs + sltr * 128;
#pragma unroll
            for (int ks = 0; ks < 2; ++ks) {
                v8s krf = *(const v8s*)(krow + ((ks * 64 + g * 16) ^ swz));
                pp[pf] = __builtin_amdgcn_mfma_f32_16x16x32_bf16(qrf[ks], krf, pp[pf], 0, 0, 0);
            }
        }
        __builtin_amdgcn_s_setprio(0);

        // --- rel-shift gather ---
        float spp[5][4];
#pragma unroll
        for (int pf = 0; pf < 5; ++pf)
#pragma unroll
            for (int t = 0; t < 4; ++t)
                spp[pf][t] = __shfl(pp[pf][t], sl[t]);

        // --- fixed-max softmax: p = exp2((ac+bd)*SCL - 8*log2e) ---
#pragma unroll
        for (int t = 0; t < 4; ++t) {
            float p[4];
#pragma unroll
            for (int jf = 0; jf < 4; ++jf) {
                float bd = esel[t] ? spp[jf + 1][t] : spp[jf][t];
                p[jf] = exp2f((ac[jf][t] + bd) * SCL - MB8);
                psac[t] += p[jf];
            }
            uint32_t w0 = cvtpk(p[0], p[1]);
            uint32_t w1 = cvtpk(p[2], p[3]);
            const int rw = g * 4 + t;
            *(uint2*)((char*)Ptw + rw * 128 + ((c15 * 8) ^ ((rw & 7) << 4))) =
                uint2{w0, w1};
        }
        asm volatile("s_waitcnt lgkmcnt(0)" ::: "memory");

        // --- PV: A-frag from Ptw (j-permuted), B-frag from staged V ---
        v8s pa[2];
#pragma unroll
        for (int ks = 0; ks < 2; ++ks)
            pa[ks] = *(const v8s*)((const char*)Ptw + c15 * 128 + ((ks * 64 + g * 16) ^ swz));
        __builtin_amdgcn_s_setprio(1);
#pragma unroll
        for (int df = 0; df < 4; ++df) {
            const char* vrow = (const char*)Vs[cur] + (df * 16 + c15) * 128;
#pragma unroll
            for (int ks = 0; ks < 2; ++ks) {
                v8s vf = *(const v8s*)(vrow + ((ks * 64 + g * 16) ^ swz));
                acc_o[df] = __builtin_amdgcn_mfma_f32_16x16x32_bf16(pa[ks], vf, acc_o[df], 0, 0, 0);
            }
        }
        __builtin_amdgcn_s_setprio(0);

        asm volatile("s_waitcnt vmcnt(0)" ::: "memory");
        __syncthreads();
    }

    // ---- epilogue: one row-sum reduce (across c15 lanes), divide, store ----
    float rinv[4];
#pragma unroll
    for (int t = 0; t < 4; ++t) {
        float l = psac[t];
#pragma unroll
        for (int m = 1; m < 16; m <<= 1) l += __shfl_xor(l, m);
        rinv[t] = 1.0f / l;
    }
#pragma unroll
    for (int df = 0; df < 4; ++df)
#pragma unroll
        for (int t = 0; t < 4; ++t) {
            int i = i0w + g * 4 + t;
            int d = df * 16 + c15;
            AV[((size_t)(i * 4 + b) << 10) + n * 64 + d] =
                f2b(acc_o[df][t] * rinv[t]);
        }
}

// ---------------- LayerNorm over last dim (1024), one row per wave ----------
__global__ __launch_bounds__(256) void ln_kernel(
    const float* __restrict__ AO, const float* __restrict__ gamma,
    const float* __restrict__ beta, float* __restrict__ out)
{
    const int w = threadIdx.x >> 6, lane = threadIdx.x & 63;
    const int row = blockIdx.x * 4 + w;
    const float4* src = (const float4*)(AO + (size_t)row * 1024);
    float4 v[4];
    float s = 0.f, sq = 0.f;
#pragma unroll
    for (int q = 0; q < 4; ++q) {
        v[q] = src[lane + q * 64];
        s += v[q].x + v[q].y + v[q].z + v[q].w;
        sq += v[q].x * v[q].x + v[q].y * v[q].y + v[q].z * v[q].z + v[q].w * v[q].w;
    }
#pragma unroll
    for (int m = 1; m < 64; m <<= 1) { s += __shfl_xor(s, m); sq += __shfl_xor(sq, m); }
    float mean = s * (1.f / 1024.f);
    float var = sq * (1.f / 1024.f) - mean * mean;
    float rstd = rsqrtf(var + 1e-5f);
    const float4* g4 = (const float4*)gamma;
    const float4* b4 = (const float4*)beta;
    float4* o4 = (float4*)(out + (size_t)row * 1024);
#pragma unroll
    for (int q = 0; q < 4; ++q) {
        float4 gg = g4[lane + q * 64], bb = b4[lane + q * 64], vv = v[q], r;
        r.x = (vv.x - mean) * rstd * gg.x + bb.x;
        r.y = (vv.y - mean) * rstd * gg.y + bb.y;
        r.z = (vv.z - mean) * rstd * gg.z + bb.z;
        r.w = (vv.w - mean) * rstd * gg.w + bb.w;
        o4[lane + q * 64] = r;
    }
}

extern "C" void kernel_launch(void* const* d_in, const int* in_sizes, int n_in,
                              void* d_out, int out_size, void* d_ws, size_t ws_size,
                              hipStream_t stream)
{
    const float* h        = (const float*)d_in[0];
    const float* r        = (const float*)d_in[1];
    const float* q_w      = (const float*)d_in[2];
    const float* k_w      = (const float*)d_in[3];
    const float* v_w      = (const float*)d_in[4];
    const float* o_w      = (const float*)d_in[5];
    const float* r_w      = (const float*)d_in[6];
    const float* r_r_bias = (const float*)d_in[7];
    const float* r_w_bias = (const float*)d_in[8];
    const float* ln_gamma = (const float*)d_in[9];
    const float* ln_beta  = (const float*)d_in[10];
    float* out = (float*)d_out;

    char* ws = (char*)d_ws;
    const size_t MB = 1u << 20;
    uint16_t* hB   = (uint16_t*)(ws + 0);        // 8MB  [m][k] bf16 (m = i*4+b)
    uint16_t* rB   = (uint16_t*)(ws + 8 * MB);   // 16MB [m][k] bf16 (m = j*4+b)
    uint16_t* Wcat = (uint16_t*)(ws + 24 * MB);  // 6MB  [nd' 0..3071][h] (qT,kT,vT)
    uint16_t* rwT  = (uint16_t*)(ws + 30 * MB);  // 2MB  [nd][h]
    uint16_t* owB  = (uint16_t*)(ws + 32 * MB);  // 2MB  [hh][nd]
    uint16_t* Qraw = (uint16_t*)(ws + 34 * MB);  // 8MB  [bn][i][d] (raw, no bias)
    uint16_t* Kt   = (uint16_t*)(ws + 50 * MB);  // 8MB  [bn][i][d]
    uint16_t* Vt   = (uint16_t*)(ws + 58 * MB);  // 8MB  [bn][d][i'] (transp+perm)
    uint16_t* Kr   = (uint16_t*)(ws + 66 * MB);  // 16MB [bn][j][d]   (ends 82MB)
    uint16_t* AV   = hB;          // alias: hB dead after gemm_qkvr
    float*    AO   = (float*)rB;  // alias: rB dead after gemm_qkvr

    prep_kernel<<<3072, 256, 0, stream>>>(h, r, o_w, q_w, k_w, v_w, r_w,
                                          (uint64_t*)hB, (uint64_t*)rB,
                                          (uint64_t*)owB, Wcat, rwT);
    gemm_qkvr<<<1280, 256, 0, stream>>>(hB, Wcat, rB, rwT,
                                        Qraw, Kt, Vt, Kr);
    attn_kernel<<<512, 512, 0, stream>>>(Qraw, Kt, Vt, Kr,
                                         r_w_bias, r_r_bias, AV);
    gemm_out<<<512, 256, 0, stream>>>(AV, owB, AO, h);
    ln_kernel<<<1024, 256, 0, stream>>>(AO, ln_gamma, ln_beta, out);
}

// Round 11
// 152.750 us; speedup vs baseline: 1.0259x; 1.0259x over previous
//
#include <hip/hip_runtime.h>
#include <stdint.h>

// RelativeAttention (Transformer-XL style), MI355X bf16-MFMA pipeline.
// SEQ=1024 RLEN=2048 BATCH=4 NH=16 DH=64 DM=1024.
// rel_shift derivation: shifted_bd[i,j] = BD[i, 1024 + j - i].
// r11 = exact re-anchor of the r7 configuration (best verified: 153.4 us).

typedef __attribute__((ext_vector_type(8))) short v8s;   // 8 x bf16
typedef __attribute__((ext_vector_type(4))) float v4f;   // MFMA acc

__device__ __forceinline__ uint16_t f2b(float x) {       // f32 -> bf16 RNE
    uint32_t u = __builtin_bit_cast(uint32_t, x);
    u += 0x7fffu + ((u >> 16) & 1u);
    return (uint16_t)(u >> 16);
}

__device__ __forceinline__ void gld16(const void* g, void* lds) {
    __builtin_amdgcn_global_load_lds(
        (const __attribute__((address_space(1))) uint32_t*)g,
        (__attribute__((address_space(3))) uint32_t*)lds, 16, 0, 0);
}

// ---------------- prep: f32->bf16 casts (h, r, o_w) + weight transposes -----
__global__ __launch_bounds__(256) void prep_kernel(
    const float* __restrict__ h, const float* __restrict__ r,
    const float* __restrict__ o_w, const float* __restrict__ q_w,
    const float* __restrict__ k_w, const float* __restrict__ v_w,
    const float* __restrict__ r_w,
    uint64_t* __restrict__ hB, uint64_t* __restrict__ rB,
    uint64_t* __restrict__ owB, uint16_t* __restrict__ Wcat,
    uint16_t* __restrict__ rwT)
{
    __shared__ float t[64][65];
    const int bid = blockIdx.x, tid = threadIdx.x;
    if (bid < 1024) {
        const int tx = bid & 15, ty = (bid >> 4) & 15, z = bid >> 8;
        const int n0 = tx * 64, h0 = ty * 64;
        const float* src = (z == 0) ? q_w : (z == 1) ? k_w : (z == 2) ? v_w : r_w;
        uint16_t* dst = (z == 3) ? rwT : Wcat + (size_t)z * 1048576;
#pragma unroll
        for (int q = 0; q < 16; ++q) {
            int idx = q * 256 + tid, rr = idx >> 6, cc = idx & 63;
            t[rr][cc] = src[(size_t)(h0 + rr) * 1024 + n0 + cc];
        }
        __syncthreads();
#pragma unroll
        for (int q = 0; q < 16; ++q) {
            int idx = q * 256 + tid, rr = idx >> 6, cc = idx & 63;
            dst[(size_t)(n0 + rr) * 1024 + h0 + cc] = f2b(t[cc][rr]);
        }
    } else {
        const float4* h4 = (const float4*)h;
        const float4* r4 = (const float4*)r;
        const float4* w4 = (const float4*)o_w;
        const int total = 1048576 + 2097152 + 262144; // float4 chunks
        for (int i = (bid - 1024) * 256 + tid; i < total; i += 2048 * 256) {
            float4 v; uint64_t* dst; int idx;
            if (i < 1048576)      { idx = i;           v = h4[idx]; dst = hB; }
            else if (i < 3145728) { idx = i - 1048576; v = r4[idx]; dst = rB; }
            else                  { idx = i - 3145728; v = w4[idx]; dst = owB; }
            uint64_t p = (uint64_t)f2b(v.x) | ((uint64_t)f2b(v.y) << 16)
                       | ((uint64_t)f2b(v.z) << 32) | ((uint64_t)f2b(v.w) << 48);
            dst[idx] = p;
        }
    }
}

// ---------------- bf16 GEMM body, C = A[M,K] * B[N,K]^T, BMx128, BK=64 ------
// m97 structure: SINGLE-buffered LDS (32KB -> 5 blocks/CU; cross-block TLP
// covers the barrier drain — dbuf at 64KB/2 blocks/CU regressed, cf. m132).
template<int MODE, int MI>
__device__ __forceinline__ void gemm_body(
    const uint16_t* __restrict__ A, const uint16_t* __restrict__ B, int K,
    int bx, int by, uint16_t* As, uint16_t* Bs,
    uint16_t* __restrict__ o0, uint16_t* __restrict__ o1,
    uint16_t* __restrict__ o2, uint16_t* __restrict__ o3,
    const float* __restrict__ bias0, const float* __restrict__ bias1,
    float* __restrict__ fo, const float* __restrict__ fres)
{
    const int tid = threadIdx.x;
    const int w = tid >> 6, lane = tid & 63;
    const int g = lane >> 4, c15 = lane & 15;
    const int m0 = by * (MI * 32), n0 = bx * 128;
    const int wr = w >> 1, wc = w & 1;

    int rowA[MI], colA[MI];
#pragma unroll
    for (int q = 0; q < MI; ++q) {
        int D = (w * MI + q) * 1024 + lane * 16;
        int row = D >> 7;
        rowA[q] = row;
        colA[q] = (D & 127) ^ ((row & 7) << 4);
    }
    int rowB[4], colB[4];
#pragma unroll
    for (int q = 0; q < 4; ++q) {
        int D = (w * 4 + q) * 1024 + lane * 16;
        int row = D >> 7;
        rowB[q] = row;
        colB[q] = (D & 127) ^ ((row & 7) << 4);
    }

    v4f acc[MI][4];
#pragma unroll
    for (int i = 0; i < MI; ++i)
#pragma unroll
        for (int j = 0; j < 4; ++j) acc[i][j] = v4f{0.f, 0.f, 0.f, 0.f};

    const char* Abase = (const char*)(A + (size_t)m0 * K);
    const char* Bbase = (const char*)(B + (size_t)n0 * K);
    const size_t ld = (size_t)K * 2;

    for (int kb = 0; kb < K; kb += 64) {
        if (kb) __syncthreads();
#pragma unroll
        for (int q = 0; q < MI; ++q)
            gld16(Abase + (size_t)rowA[q] * ld + (size_t)kb * 2 + colA[q],
                  (char*)As + (w * MI + q) * 1024);
#pragma unroll
        for (int q = 0; q < 4; ++q)
            gld16(Bbase + (size_t)rowB[q] * ld + (size_t)kb * 2 + colB[q],
                  (char*)Bs + (w * 4 + q) * 1024);
        asm volatile("s_waitcnt vmcnt(0)" ::: "memory");
        __syncthreads();

        v8s af[MI][2], bf[4][2];
#pragma unroll
        for (int mi = 0; mi < MI; ++mi) {
            int row = wr * (MI * 16) + mi * 16 + c15;
#pragma unroll
            for (int ks = 0; ks < 2; ++ks) {
                int cl = ks * 64 + g * 16;
                af[mi][ks] = *(const v8s*)((const char*)As + row * 128 + (cl ^ ((row & 7) << 4)));
            }
        }
#pragma unroll
        for (int ni = 0; ni < 4; ++ni) {
            int row = wc * 64 + ni * 16 + c15;
#pragma unroll
            for (int ks = 0; ks < 2; ++ks) {
                int cl = ks * 64 + g * 16;
                bf[ni][ks] = *(const v8s*)((const char*)Bs + row * 128 + (cl ^ ((row & 7) << 4)));
            }
        }
#pragma unroll
        for (int mi = 0; mi < MI; ++mi)
#pragma unroll
            for (int ni = 0; ni < 4; ++ni)
#pragma unroll
                for (int ks = 0; ks < 2; ++ks)
                    acc[mi][ni] = __builtin_amdgcn_mfma_f32_16x16x32_bf16(
                        af[mi][ks], bf[ni][ks], acc[mi][ni], 0, 0, 0);
    }

#pragma unroll
    for (int mi = 0; mi < MI; ++mi)
#pragma unroll
        for (int ni = 0; ni < 4; ++ni)
#pragma unroll
            for (int t = 0; t < 4; ++t) {
                int row = m0 + wr * (MI * 16) + mi * 16 + g * 4 + t; // C row
                int col = n0 + wc * 64 + ni * 16 + c15;              // C col
                float v = acc[mi][ni][t];
                if (MODE == 0) {
                    int seg = col >> 10, nd = col & 1023;
                    int i = row >> 2, b = row & 3, n = nd >> 6, d = nd & 63;
                    int bn = b * 16 + n;
                    if (seg == 0) {
                        o0[(bn << 16) + (i << 6) + d] = f2b(v + bias0[nd]);
                        o1[(bn << 16) + (i << 6) + d] = f2b(v + bias1[nd]);
                    } else if (seg == 1) {
                        o2[(bn << 16) + (i << 6) + d] = f2b(v);
                    } else {
                        // V transposed + j-permuted within each 64-block:
                        // j = f*16+c stored at position c*4+f (must match P store)
                        int il = i & 63;
                        int iperm = (i & ~63) | ((il & 15) * 4 + (il >> 4));
                        o3[(bn << 16) + (d << 10) + iperm] = f2b(v);
                    }
                } else if (MODE == 1) {
                    int j = row >> 2, b = row & 3, n = col >> 6, d = col & 63;
                    int bn = b * 16 + n;
                    o0[(bn << 17) + (j << 6) + d] = f2b(v);
                } else {
                    size_t idx = (size_t)row * 1024 + col;
                    fo[idx] = v + fres[idx];   // residual add in f32
                }
            }
}

// merged projection GEMMs, 2D-XCD-swizzled (bid%8 = XCD)
__global__ __launch_bounds__(256) void gemm_qkvr(
    const uint16_t* __restrict__ hB, const uint16_t* __restrict__ Wcat,
    const uint16_t* __restrict__ rB, const uint16_t* __restrict__ rwT,
    uint16_t* __restrict__ Qw, uint16_t* __restrict__ Qr,
    uint16_t* __restrict__ Kt, uint16_t* __restrict__ Vt,
    uint16_t* __restrict__ Kr,
    const float* __restrict__ b0, const float* __restrict__ b1)
{
    __shared__ __align__(16) uint16_t As[128 * 64];
    __shared__ __align__(16) uint16_t Bs[128 * 64];
    const int bid = blockIdx.x;
    if (bid < 768) {
        const int x = bid & 7, l = bid >> 3;          // l in [0,96)
        const int by = (x >> 1) * 8 + l / 12;
        const int bx = (x & 1) * 12 + l % 12;
        gemm_body<0, 4>(hB, Wcat, 1024, bx, by, As, Bs,
                        Qw, Qr, Kt, Vt, b0, b1, nullptr, nullptr);
    } else {
        const int b2 = bid - 768;
        const int x = b2 & 7, l = b2 >> 3;            // l in [0,64)
        const int by = x * 8 + l / 8;
        const int bx = l % 8;
        gemm_body<1, 4>(rB, rwT, 1024, bx, by, As, Bs,
                        Kr, nullptr, nullptr, nullptr, nullptr, nullptr,
                        nullptr, nullptr);
    }
}

// out proj: BM=64 tiles -> 512 blocks, XCD x owns m-rows [8x,+8)
__global__ __launch_bounds__(256) void gemm_out(
    const uint16_t* __restrict__ AV, const uint16_t* __restrict__ owB,
    float* __restrict__ AO, const float* __restrict__ hres)
{
    __shared__ __align__(16) uint16_t As[64 * 64];
    __shared__ __align__(16) uint16_t Bs[128 * 64];
    const int x = blockIdx.x & 7, l = blockIdx.x >> 3;  // l in [0,64)
    const int by = x * 8 + l / 8;
    const int bx = l % 8;
    gemm_body<2, 2>(AV, owB, 1024, bx, by, As, Bs,
                    nullptr, nullptr, nullptr, nullptr, nullptr, nullptr,
                    AO, hres);
}

// ---------------- fused rel-shift flash attention ---------------------------
// Grid 512 blocks x 512 threads (8 waves); XCD-swizzled (8 i-tiles of a bn
// share one XCD L2); 2 blocks/CU (80KB LDS), 16 waves/CU. Each wave owns ONE
// 16-row strip (i0w = i0 + 16w). Per j-tile: double-buffered K/V staging +
// 256-row Kr ring (64 new rows/tile, one chunk per wave) via global_load_lds
// with pre-swizzled source; rel-shift via 20 lane shuffles; FIXED-max softmax
// (M=8, exact by shift invariance); P stored j-permuted (col' = c15*4+jf)
// via v_cvt_pk_bf16_f32; V permuted identically in gemm<0>.
__global__ __launch_bounds__(512, 4) void attn_kernel(
    const uint16_t* __restrict__ Qw, const uint16_t* __restrict__ Qr,
    const uint16_t* __restrict__ Kt, const uint16_t* __restrict__ Vt,
    const uint16_t* __restrict__ Kr, uint16_t* __restrict__ AV)
{
    __shared__ __align__(16) uint16_t Ks[2][4096];   // 8KB ea: 64 j x 64 d
    __shared__ __align__(16) uint16_t Vs[2][4096];   // 8KB ea: 64 d x 64 j'
    __shared__ __align__(16) uint16_t Krs[16384];    // 32KB ring: 256 rows
    __shared__ __align__(16) uint16_t Ptl[8][1024];  // 16KB: per-wave 16x64

    const int tid = threadIdx.x, w = tid >> 6, lane = tid & 63;
    const int g = lane >> 4, c15 = lane & 15;
    const int bid = blockIdx.x;
    const int xcd = bid & 7, slot = bid >> 3;
    const int it = slot & 7, bn = ((slot >> 3) << 3) | xcd;
    const int b = bn >> 4, n = bn & 15;
    const int i0 = it * 128, i0w = i0 + w * 16;
    const int B0 = 897 - i0;                 // lowest Kr row of jt=0 window

    const uint16_t* qwp = Qw + ((size_t)bn << 16);
    const uint16_t* qrp = Qr + ((size_t)bn << 16);
    const char* ktp = (const char*)(Kt + ((size_t)bn << 16));
    const char* vtp = (const char*)(Vt + ((size_t)bn << 16));
    const char* krp = (const char*)(Kr + ((size_t)bn << 17));

    const int rsub = lane >> 3;              // staging: row-within-8-chunk
    const int csrc = ((lane & 7) ^ rsub) << 4;  // pre-swizzled source col
    const int dsto = lane * 16;              // linear LDS dest
    const int swz = (c15 & 7) << 4;          // read-side XOR term

    // rel-shift shuffle constants: e = 15 + c15 - (g*4+t)
    int sl[4], esel[4];
#pragma unroll
    for (int t = 0; t < 4; ++t) {
        int e = 15 + c15 - (g * 4 + t);
        sl[t] = g * 16 + (e & 15);
        esel[t] = e >> 4;
    }

    v8s qwf[2], qrf[2];
#pragma unroll
    for (int ks = 0; ks < 2; ++ks) {
        qwf[ks] = *(const v8s*)(qwp + ((i0w + c15) << 6) + ks * 32 + g * 8);
        qrf[ks] = *(const v8s*)(qrp + ((i0w + c15) << 6) + ks * 32 + g * 8);
    }

    v4f acc_o[4];
    float psac[4];
#pragma unroll
    for (int df = 0; df < 4; ++df) acc_o[df] = v4f{0.f, 0.f, 0.f, 0.f};
#pragma unroll
    for (int t = 0; t < 4; ++t) psac[t] = 0.f;

    uint16_t* Ptw = Ptl[w];
    const float SCL = 0.18033688f;   // 0.125 * log2(e)
    const float MB8 = 11.54156032f;  // 8 * log2(e)

    // ---- prologue staging: K/V tile 0 (chunk w each) + Kr rows B0..B0+191
    gld16(ktp + (size_t)(w * 8 + rsub) * 128 + csrc,
          (char*)Ks[0] + w * 1024 + dsto);
    gld16(vtp + (size_t)(w * 8 + rsub) * 2048 + csrc,
          (char*)Vs[0] + w * 1024 + dsto);
#pragma unroll
    for (int qq = 0; qq < 3; ++qq) {
        const int chunk = qq * 8 + w;
        const int rg = B0 + chunk * 8 + rsub;   // in [1, 1088]
        gld16(krp + (size_t)rg * 128 + csrc, (char*)Krs + chunk * 1024 + dsto);
    }
    asm volatile("s_waitcnt vmcnt(0)" ::: "memory");
    __syncthreads();

    for (int jt = 0; jt < 16; ++jt) {
        const int cur = jt & 1;
        if (jt < 15) {
            const int j1 = (jt + 1) * 64;
            gld16(ktp + (size_t)(j1 + w * 8 + rsub) * 128 + csrc,
                  (char*)Ks[cur ^ 1] + w * 1024 + dsto);
            gld16(vtp + (size_t)(w * 8 + rsub) * 2048 + j1 * 2 + csrc,
                  (char*)Vs[cur ^ 1] + w * 1024 + dsto);
            const int sbase = (192 + 64 * jt) & 255;   // ring write slots
            int rg = B0 + 192 + 64 * jt + w * 8 + rsub;
            rg = rg > 2047 ? 2047 : rg;  // clamp: only u=79 (never gathered)
            gld16(krp + (size_t)rg * 128 + csrc,
                  (char*)Krs + (sbase + w * 8) * 128 + dsto);
        }

        // --- AC = Qw x K^T (64 cols) + BD = Qr x KrWin^T (80 cols) ---
        v4f ac[4];
#pragma unroll
        for (int jf = 0; jf < 4; ++jf) ac[jf] = v4f{0.f, 0.f, 0.f, 0.f};
        v4f pp[5];
#pragma unroll
        for (int pf = 0; pf < 5; ++pf) pp[pf] = v4f{0.f, 0.f, 0.f, 0.f};

        __builtin_amdgcn_s_setprio(1);
#pragma unroll
        for (int jf = 0; jf < 4; ++jf) {
            const char* krow = (const char*)Ks[cur] + (jf * 16 + c15) * 128;
#pragma unroll
            for (int ks = 0; ks < 2; ++ks) {
                v8s kf = *(const v8s*)(krow + ((ks * 64 + g * 16) ^ swz));
                ac[jf] = __builtin_amdgcn_mfma_f32_16x16x32_bf16(qwf[ks], kf, ac[jf], 0, 0, 0);
            }
        }
        const int krbase = 64 * jt + 112 - 16 * w + c15;  // ring slot (+c15)
#pragma unroll
        for (int pf = 0; pf < 5; ++pf) {
            const int sltr = (krbase + 16 * pf) & 255;
            const char* krow = (const char*)Krs + sltr * 128;
#pragma unroll
            for (int ks = 0; ks < 2; ++ks) {
                v8s krf = *(const v8s*)(krow + ((ks * 64 + g * 16) ^ swz));
                pp[pf] = __builtin_amdgcn_mfma_f32_16x16x32_bf16(qrf[ks], krf, pp[pf], 0, 0, 0);
            }
        }
        __builtin_amdgcn_s_setprio(0);

        // --- rel-shift gather ---
        float spp[5][4];
#pragma unroll
        for (int pf = 0; pf < 5; ++pf)
#pragma unroll
            for (int t = 0; t < 4; ++t)
                spp[pf][t] = __shfl(pp[pf][t], sl[t]);

        // --- fixed-max softmax: p = exp2((ac+bd)*SCL - 8*log2e) ---
#pragma unroll
        for (int t = 0; t < 4; ++t) {
            float p[4];
#pragma unroll
            for (int jf = 0; jf < 4; ++jf) {
                float bd = esel[t] ? spp[jf + 1][t] : spp[jf][t];
                p[jf] = exp2f((ac[jf][t] + bd) * SCL - MB8);
                psac[t] += p[jf];
            }
            uint32_t w0, w1;
            asm("v_cvt_pk_bf16_f32 %0, %1, %2" : "=v"(w0) : "v"(p[0]), "v"(p[1]));
            asm("v_cvt_pk_bf16_f32 %0, %1, %2" : "=v"(w1) : "v"(p[2]), "v"(p[3]));
            const int rw = g * 4 + t;
            *(uint2*)((char*)Ptw + rw * 128 + ((c15 * 8) ^ ((rw & 7) << 4))) =
                uint2{w0, w1};
        }
        asm volatile("s_waitcnt lgkmcnt(0)" ::: "memory");

        // --- PV: A-frag from Ptw (j-permuted), B-frag from staged V ---
        v8s pa[2];
#pragma unroll
        for (int ks = 0; ks < 2; ++ks)
            pa[ks] = *(const v8s*)((const char*)Ptw + c15 * 128 + ((ks * 64 + g * 16) ^ swz));
        __builtin_amdgcn_s_setprio(1);
#pragma unroll
        for (int df = 0; df < 4; ++df) {
            const char* vrow = (const char*)Vs[cur] + (df * 16 + c15) * 128;
#pragma unroll
            for (int ks = 0; ks < 2; ++ks) {
                v8s vf = *(const v8s*)(vrow + ((ks * 64 + g * 16) ^ swz));
                acc_o[df] = __builtin_amdgcn_mfma_f32_16x16x32_bf16(pa[ks], vf, acc_o[df], 0, 0, 0);
            }
        }
        __builtin_amdgcn_s_setprio(0);

        asm volatile("s_waitcnt vmcnt(0)" ::: "memory");
        __syncthreads();
    }

    // ---- epilogue: one row-sum reduce (across c15 lanes), divide, store ----
    float rinv[4];
#pragma unroll
    for (int t = 0; t < 4; ++t) {
        float l = psac[t];
#pragma unroll
        for (int m = 1; m < 16; m <<= 1) l += __shfl_xor(l, m);
        rinv[t] = 1.0f / l;
    }
#pragma unroll
    for (int df = 0; df < 4; ++df)
#pragma unroll
        for (int t = 0; t < 4; ++t) {
            int i = i0w + g * 4 + t;
            int d = df * 16 + c15;
            AV[((size_t)(i * 4 + b) << 10) + n * 64 + d] =
                f2b(acc_o[df][t] * rinv[t]);
        }
}

// ---------------- LayerNorm over last dim (1024), one row per wave ----------
__global__ __launch_bounds__(256) void ln_kernel(
    const float* __restrict__ AO, const float* __restrict__ gamma,
    const float* __restrict__ beta, float* __restrict__ out)
{
    const int w = threadIdx.x >> 6, lane = threadIdx.x & 63;
    const int row = blockIdx.x * 4 + w;
    const float4* src = (const float4*)(AO + (size_t)row * 1024);
    float4 v[4];
    float s = 0.f, sq = 0.f;
#pragma unroll
    for (int q = 0; q < 4; ++q) {
        v[q] = src[lane + q * 64];
        s += v[q].x + v[q].y + v[q].z + v[q].w;
        sq += v[q].x * v[q].x + v[q].y * v[q].y + v[q].z * v[q].z + v[q].w * v[q].w;
    }
#pragma unroll
    for (int m = 1; m < 64; m <<= 1) { s += __shfl_xor(s, m); sq += __shfl_xor(sq, m); }
    float mean = s * (1.f / 1024.f);
    float var = sq * (1.f / 1024.f) - mean * mean;
    float rstd = rsqrtf(var + 1e-5f);
    const float4* g4 = (const float4*)gamma;
    const float4* b4 = (const float4*)beta;
    float4* o4 = (float4*)(out + (size_t)row * 1024);
#pragma unroll
    for (int q = 0; q < 4; ++q) {
        float4 gg = g4[lane + q * 64], bb = b4[lane + q * 64], vv = v[q], r;
        r.x = (vv.x - mean) * rstd * gg.x + bb.x;
        r.y = (vv.y - mean) * rstd * gg.y + bb.y;
        r.z = (vv.z - mean) * rstd * gg.z + bb.z;
        r.w = (vv.w - mean) * rstd * gg.w + bb.w;
        o4[lane + q * 64] = r;
    }
}

extern "C" void kernel_launch(void* const* d_in, const int* in_sizes, int n_in,
                              void* d_out, int out_size, void* d_ws, size_t ws_size,
                              hipStream_t stream)
{
    const float* h        = (const float*)d_in[0];
    const float* r        = (const float*)d_in[1];
    const float* q_w      = (const float*)d_in[2];
    const float* k_w      = (const float*)d_in[3];
    const float* v_w      = (const float*)d_in[4];
    const float* o_w      = (const float*)d_in[5];
    const float* r_w      = (const float*)d_in[6];
    const float* r_r_bias = (const float*)d_in[7];
    const float* r_w_bias = (const float*)d_in[8];
    const float* ln_gamma = (const float*)d_in[9];
    const float* ln_beta  = (const float*)d_in[10];
    float* out = (float*)d_out;

    char* ws = (char*)d_ws;
    const size_t MB = 1u << 20;
    uint16_t* hB   = (uint16_t*)(ws + 0);        // 8MB  [m][k] bf16 (m = i*4+b)
    uint16_t* rB   = (uint16_t*)(ws + 8 * MB);   // 16MB [m][k] bf16 (m = j*4+b)
    uint16_t* Wcat = (uint16_t*)(ws + 24 * MB);  // 6MB  [nd' 0..3071][h] (qT,kT,vT)
    uint16_t* rwT  = (uint16_t*)(ws + 30 * MB);  // 2MB  [nd][h]
    uint16_t* owB  = (uint16_t*)(ws + 32 * MB);  // 2MB  [hh][nd]
    uint16_t* Qw   = (uint16_t*)(ws + 34 * MB);  // 8MB  [bn][i][d] (+r_w_bias)
    uint16_t* Qr   = (uint16_t*)(ws + 42 * MB);  // 8MB  [bn][i][d] (+r_r_bias)
    uint16_t* Kt   = (uint16_t*)(ws + 50 * MB);  // 8MB  [bn][i][d]
    uint16_t* Vt   = (uint16_t*)(ws + 58 * MB);  // 8MB  [bn][d][i'] (transp+perm)
    uint16_t* Kr   = (uint16_t*)(ws + 66 * MB);  // 16MB [bn][j][d]   (ends 82MB)
    uint16_t* AV   = hB;          // alias: hB dead after gemm_qkvr
    float*    AO   = (float*)rB;  // alias: rB dead after gemm_qkvr

    prep_kernel<<<3072, 256, 0, stream>>>(h, r, o_w, q_w, k_w, v_w, r_w,
                                          (uint64_t*)hB, (uint64_t*)rB,
                                          (uint64_t*)owB, Wcat, rwT);
    gemm_qkvr<<<1280, 256, 0, stream>>>(hB, Wcat, rB, rwT,
                                        Qw, Qr, Kt, Vt, Kr, r_w_bias, r_r_bias);
    attn_kernel<<<512, 512, 0, stream>>>(Qw, Qr, Kt, Vt, Kr, AV);
    gemm_out<<<512, 256, 0, stream>>>(AV, owB, AO, h);
    ln_kernel<<<1024, 256, 0, stream>>>(AO, ln_gamma, ln_beta, out);
}